// Round 3
// baseline (53.433 us; speedup 1.0000x reference)
//
#include <hip/hip_runtime.h>

// out[row, j] for row in [0, 64*4096), j in [0,256):
//   j < 255 : sin(tau[row]*w[j] + b[j])
//   j == 255: tau[row]*w0 + b0
// 64 threads per row, 4 consecutive outputs per thread (16B store).
// Each thread processes 2 rows per iteration (2x dwordx4 nontemporal stores
// in flight); w/b fragments are row-invariant per thread -> registers.

typedef float f32x4 __attribute__((ext_vector_type(4)));

__global__ __launch_bounds__(256) void SineActivation_59742995087547_kernel(
    const float* __restrict__ tau,
    const float* __restrict__ w,
    const float* __restrict__ b,
    const float* __restrict__ w0,
    const float* __restrict__ b0,
    float* __restrict__ out,
    int n_rows)
{
    const int tid = threadIdx.x;
    const int j0 = (tid & 63) * 4;        // 64 threads cover 256 outputs
    const int row_in_blk = tid >> 6;      // 4 row-slots per 256-thread block

    const bool last = (j0 == 252);        // this thread's 4th elem is j=255
    f32x4 wv, bv;
    wv.x = w[j0 + 0]; bv.x = b[j0 + 0];
    wv.y = w[j0 + 1]; bv.y = b[j0 + 1];
    wv.z = w[j0 + 2]; bv.z = b[j0 + 2];
    if (last) { wv.w = w0[0];     bv.w = b0[0]; }
    else      { wv.w = w[j0 + 3]; bv.w = b[j0 + 3]; }

    // 8 rows per block per iteration: 4 wave-slots x 2 rows each.
    const int row_stride = gridDim.x * 8;
    for (int row = blockIdx.x * 8 + row_in_blk; row < n_rows; row += row_stride) {
        const int row2 = row + 4;
        const float t0 = tau[row];
        const float t1 = (row2 < n_rows) ? tau[row2] : 0.0f;

        f32x4 o0, o1;
        o0.x = __sinf(fmaf(t0, wv.x, bv.x));
        o0.y = __sinf(fmaf(t0, wv.y, bv.y));
        o0.z = __sinf(fmaf(t0, wv.z, bv.z));
        const float lin0 = fmaf(t0, wv.w, bv.w);
        o0.w = last ? lin0 : __sinf(lin0);

        o1.x = __sinf(fmaf(t1, wv.x, bv.x));
        o1.y = __sinf(fmaf(t1, wv.y, bv.y));
        o1.z = __sinf(fmaf(t1, wv.z, bv.z));
        const float lin1 = fmaf(t1, wv.w, bv.w);
        o1.w = last ? lin1 : __sinf(lin1);

        __builtin_nontemporal_store(o0, reinterpret_cast<f32x4*>(out + (size_t)row * 256 + j0));
        if (row2 < n_rows) {
            __builtin_nontemporal_store(o1, reinterpret_cast<f32x4*>(out + (size_t)row2 * 256 + j0));
        }
    }
}

extern "C" void kernel_launch(void* const* d_in, const int* in_sizes, int n_in,
                              void* d_out, int out_size, void* d_ws, size_t ws_size,
                              hipStream_t stream) {
    const float* tau = (const float*)d_in[0];
    const float* w   = (const float*)d_in[1];
    const float* b   = (const float*)d_in[2];
    const float* w0  = (const float*)d_in[3];
    const float* b0  = (const float*)d_in[4];
    float* out = (float*)d_out;

    const int n_rows = in_sizes[0];       // 64*4096 = 262144 rows of 256
    const int grid = 2048;                // 8 blocks/CU, 16 iters/thread
    SineActivation_59742995087547_kernel<<<grid, 256, 0, stream>>>(
        tau, w, b, w0, b0, out, n_rows);
}

// Round 4
// 46.642 us; speedup vs baseline: 1.1456x; 1.1456x over previous
//
#include <hip/hip_runtime.h>

// out[row, j] for row in [0, 64*4096), j in [0,256):
//   j < 255 : sin(tau[row]*w[j] + b[j])
//   j == 255: tau[row]*w0 + b0
// 64 threads per row, 4 consecutive outputs per thread (16B store).
// Each thread processes 2 rows per iteration (2x dwordx4 stores in flight,
// PLAIN stores — nontemporal regressed 46.9->53.4 us in round 2/3).
// w/b fragments are row-invariant per thread -> registers.

typedef float f32x4 __attribute__((ext_vector_type(4)));

__global__ __launch_bounds__(256) void SineActivation_59742995087547_kernel(
    const float* __restrict__ tau,
    const float* __restrict__ w,
    const float* __restrict__ b,
    const float* __restrict__ w0,
    const float* __restrict__ b0,
    float* __restrict__ out,
    int n_rows)
{
    const int tid = threadIdx.x;
    const int j0 = (tid & 63) * 4;        // 64 threads cover 256 outputs
    const int row_in_blk = tid >> 6;      // 4 row-slots per 256-thread block

    const bool last = (j0 == 252);        // this thread's 4th elem is j=255
    f32x4 wv, bv;
    wv.x = w[j0 + 0]; bv.x = b[j0 + 0];
    wv.y = w[j0 + 1]; bv.y = b[j0 + 1];
    wv.z = w[j0 + 2]; bv.z = b[j0 + 2];
    if (last) { wv.w = w0[0];     bv.w = b0[0]; }
    else      { wv.w = w[j0 + 3]; bv.w = b[j0 + 3]; }

    // 8 rows per block per iteration: 4 wave-slots x 2 rows each.
    const int row_stride = gridDim.x * 8;
    int row = blockIdx.x * 8 + row_in_blk;
    for (; row + 4 < n_rows; row += row_stride) {
        const int row2 = row + 4;
        const float t0 = tau[row];
        const float t1 = tau[row2];

        f32x4 o0, o1;
        o0.x = __sinf(fmaf(t0, wv.x, bv.x));
        o0.y = __sinf(fmaf(t0, wv.y, bv.y));
        o0.z = __sinf(fmaf(t0, wv.z, bv.z));
        const float lin0 = fmaf(t0, wv.w, bv.w);
        o0.w = last ? lin0 : __sinf(lin0);

        o1.x = __sinf(fmaf(t1, wv.x, bv.x));
        o1.y = __sinf(fmaf(t1, wv.y, bv.y));
        o1.z = __sinf(fmaf(t1, wv.z, bv.z));
        const float lin1 = fmaf(t1, wv.w, bv.w);
        o1.w = last ? lin1 : __sinf(lin1);

        *reinterpret_cast<f32x4*>(out + (size_t)row  * 256 + j0) = o0;
        *reinterpret_cast<f32x4*>(out + (size_t)row2 * 256 + j0) = o1;
    }
    // Generic tail (not reached for n_rows % (gridDim*8) == 0).
    if (row < n_rows) {
        const float t0 = tau[row];
        f32x4 o0;
        o0.x = __sinf(fmaf(t0, wv.x, bv.x));
        o0.y = __sinf(fmaf(t0, wv.y, bv.y));
        o0.z = __sinf(fmaf(t0, wv.z, bv.z));
        const float lin0 = fmaf(t0, wv.w, bv.w);
        o0.w = last ? lin0 : __sinf(lin0);
        *reinterpret_cast<f32x4*>(out + (size_t)row * 256 + j0) = o0;
    }
}

extern "C" void kernel_launch(void* const* d_in, const int* in_sizes, int n_in,
                              void* d_out, int out_size, void* d_ws, size_t ws_size,
                              hipStream_t stream) {
    const float* tau = (const float*)d_in[0];
    const float* w   = (const float*)d_in[1];
    const float* b   = (const float*)d_in[2];
    const float* w0  = (const float*)d_in[3];
    const float* b0  = (const float*)d_in[4];
    float* out = (float*)d_out;

    const int n_rows = in_sizes[0];       // 64*4096 = 262144 rows of 256
    const int grid = 2048;                // 8 blocks/CU, 16 iters/thread
    SineActivation_59742995087547_kernel<<<grid, 256, 0, stream>>>(
        tau, w, b, w0, b0, out, n_rows);
}

// Round 5
// 46.164 us; speedup vs baseline: 1.1574x; 1.0103x over previous
//
#include <hip/hip_runtime.h>

// out[row, j] for row in [0, 64*4096), j in [0,256):
//   j < 255 : sin(tau[row]*w[j] + b[j])
//   j == 255: tau[row]*w0 + b0
// 64 threads per row, 4 consecutive outputs per thread (16B store).
// Each wave-slot handles an ADJACENT row pair (one 8B tau load) and
// prefetches the next iteration's tau pair before computing the current
// one, so the HBM/L2 load latency never sits on the store critical path.
// Plain stores (nontemporal regressed 46.9->53.4 us, round 3).

typedef float f32x4 __attribute__((ext_vector_type(4)));
typedef float f32x2 __attribute__((ext_vector_type(2)));

__global__ __launch_bounds__(256) void SineActivation_59742995087547_kernel(
    const float* __restrict__ tau,
    const float* __restrict__ w,
    const float* __restrict__ b,
    const float* __restrict__ w0,
    const float* __restrict__ b0,
    float* __restrict__ out,
    int n_rows)
{
    const int tid = threadIdx.x;
    const int j0 = (tid & 63) * 4;        // 64 threads cover 256 outputs
    const int slot = tid >> 6;            // 4 wave-slots per 256-thread block

    const bool last = (j0 == 252);        // this thread's 4th elem is j=255
    f32x4 wv, bv;
    wv.x = w[j0 + 0]; bv.x = b[j0 + 0];
    wv.y = w[j0 + 1]; bv.y = b[j0 + 1];
    wv.z = w[j0 + 2]; bv.z = b[j0 + 2];
    if (last) { wv.w = w0[0];     bv.w = b0[0]; }
    else      { wv.w = w[j0 + 3]; bv.w = b[j0 + 3]; }

    auto emit = [&](float tval, size_t r) {
        f32x4 o;
        o.x = __sinf(fmaf(tval, wv.x, bv.x));
        o.y = __sinf(fmaf(tval, wv.y, bv.y));
        o.z = __sinf(fmaf(tval, wv.z, bv.z));
        const float lin = fmaf(tval, wv.w, bv.w);
        o.w = last ? lin : __sinf(lin);
        *reinterpret_cast<f32x4*>(out + r * 256 + j0) = o;
    };

    // 8 rows per block per iteration: 4 wave-slots x 2 adjacent rows each.
    const int stride = gridDim.x * 8;
    int row = blockIdx.x * 8 + slot * 2;
    const int pairs_end = n_rows - 1;     // row+1 < n_rows  <=>  row < pairs_end

    if (row < pairs_end) {
        f32x2 t = *reinterpret_cast<const f32x2*>(tau + row);  // 8B-aligned (row even)
        int next;
        for (;;) {
            next = row + stride;
            const bool has_next = (next < pairs_end);
            f32x2 tn = t;
            if (has_next) tn = *reinterpret_cast<const f32x2*>(tau + next);  // prefetch

            emit(t.x, (size_t)row);
            emit(t.y, (size_t)row + 1);

            if (!has_next) break;
            row = next; t = tn;
        }
        row = next;
    }
    // Single-row tail (not reached when n_rows % (gridDim*8) == 0).
    for (; row < n_rows; row += stride) {
        emit(tau[row], (size_t)row);
    }
}

extern "C" void kernel_launch(void* const* d_in, const int* in_sizes, int n_in,
                              void* d_out, int out_size, void* d_ws, size_t ws_size,
                              hipStream_t stream) {
    const float* tau = (const float*)d_in[0];
    const float* w   = (const float*)d_in[1];
    const float* b   = (const float*)d_in[2];
    const float* w0  = (const float*)d_in[3];
    const float* b0  = (const float*)d_in[4];
    float* out = (float*)d_out;

    const int n_rows = in_sizes[0];       // 64*4096 = 262144 rows of 256
    const int grid = 2048;                // 8 blocks/CU, 16 iters/thread
    SineActivation_59742995087547_kernel<<<grid, 256, 0, stream>>>(
        tau, w, b, w0, b0, out, n_rows);
}